// Round 3
// baseline (1432.134 us; speedup 1.0000x reference)
//
#include <hip/hip_runtime.h>
#include <hip/hip_bf16.h>

#define N_NODES 100000
#define N_EDGES 1600000
#define Y_ELEMS (16 * N_NODES * 16)            // [k-major within node]: Y[n][k][f]
#define Y_BYTES ((size_t)Y_ELEMS * 2)          // 51.2 MB bf16

__global__ __launch_bounds__(256) void zero_out_kernel(float4* __restrict__ out, int n4) {
    int i = blockIdx.x * 256 + threadIdx.x;
    if (i < n4) out[i] = make_float4(0.f, 0.f, 0.f, 0.f);
}

__device__ __forceinline__ unsigned short f2bf(float f) {
    __hip_bfloat16 h = __float2bfloat16(f);
    return *(unsigned short*)&h;
}

// Stage 1: Y[n][k][f] (bf16) = sum_i x[n][i] * W[k][i][f]
// wave-per-node: 64 lanes = 16 k-cells x 4 f-quads; W column held in registers,
// amortized over ~25 nodes per wave. x row broadcast (all lanes same address).
__global__ __launch_bounds__(256) void stage1_xw(
    const float* __restrict__ x,       // [N_NODES,16]
    const float* __restrict__ w,       // [16][16][16] = [k][i][f]
    unsigned short* __restrict__ Y)    // [N_NODES][16][16] bf16
{
    const int lane = threadIdx.x & 63;
    const int k  = lane >> 2;          // 0..15
    const int fq = lane & 3;           // 0..3  (features fq*4 .. fq*4+3)
    const int gwave  = blockIdx.x * 4 + (threadIdx.x >> 6);
    const int nwaves = gridDim.x * 4;

    float4 wr[16];                     // W[k][i][fq*4..+3], i = 0..15
#pragma unroll
    for (int i = 0; i < 16; ++i)
        wr[i] = *(const float4*)(w + k * 256 + i * 16 + fq * 4);

    for (int n = gwave; n < N_NODES; n += nwaves) {
        const float4* xr = (const float4*)(x + (size_t)n * 16);
        float xs[16];
#pragma unroll
        for (int q = 0; q < 4; ++q) {
            float4 t4 = xr[q];
            xs[4*q+0] = t4.x; xs[4*q+1] = t4.y; xs[4*q+2] = t4.z; xs[4*q+3] = t4.w;
        }
        float4 acc = make_float4(0.f, 0.f, 0.f, 0.f);
#pragma unroll
        for (int i = 0; i < 16; ++i) {
            acc.x += xs[i] * wr[i].x; acc.y += xs[i] * wr[i].y;
            acc.z += xs[i] * wr[i].z; acc.w += xs[i] * wr[i].w;
        }
        ushort4 o;
        o.x = f2bf(acc.x); o.y = f2bf(acc.y); o.z = f2bf(acc.z); o.w = f2bf(acc.w);
        // lanes cover the node's full 512B row contiguously
        *(ushort4*)(Y + (size_t)n * 256 + k * 16 + fq * 4) = o;
    }
}

// Stage 2: one edge per lane. Gather 2x64B chunks of Y (cells k0,k0+1 and
// k0+4,k0+5), weighted-sum into msg[16], scatter-add with fp32 HW atomics.
__device__ __forceinline__ void fma_bf2(unsigned int u, float t, float& e0, float& e1) {
    e0 += t * __uint_as_float(u << 16);
    e1 += t * __uint_as_float(u & 0xffff0000u);
}

__global__ __launch_bounds__(256) void stage2_edges(
    const int*   __restrict__ edge_index,  // [2, N_EDGES]
    const float* __restrict__ edge_attr,   // [N_EDGES, 2]
    const unsigned short* __restrict__ Y,  // [N_NODES][16][16] bf16
    float*       __restrict__ out)         // [N_NODES,16], pre-zeroed
{
    const int e = blockIdx.x * 256 + threadIdx.x;
    if (e >= N_EDGES) return;

    const int row = edge_index[e];
    const int col = edge_index[N_EDGES + e];
    const float2 attr = ((const float2*)edge_attr)[e];

    float fu = (attr.x + 1.0f) * 1.5f;
    int iu = (int)fu; iu = iu < 0 ? 0 : (iu > 2 ? 2 : iu);
    const float wu1 = fu - (float)iu;
    const float wu0 = 1.0f - wu1;

    float fv = (attr.y + 1.0f) * 1.5f;
    int iv = (int)fv; iv = iv < 0 ? 0 : (iv > 2 ? 2 : iv);
    const float wv1 = fv - (float)iv;
    const float wv0 = 1.0f - wv1;

    const float t00 = wu0 * wv0, t01 = wu0 * wv1;
    const float t10 = wu1 * wv0, t11 = wu1 * wv1;
    const int k0 = iu * 4 + iv;

    const unsigned short* base = Y + (size_t)col * 256 + k0 * 16;
    const uint4* b4 = (const uint4*)base;        // 32B-aligned, 16B ok
    uint4 a0 = b4[0];   // cell k0,   f0..7
    uint4 a1 = b4[1];   // cell k0,   f8..15
    uint4 b0 = b4[2];   // cell k0+1, f0..7
    uint4 b1 = b4[3];   // cell k0+1, f8..15
    const uint4* c4 = (const uint4*)(base + 64); // + 4 cells
    uint4 c0 = c4[0];   // cell k0+4, f0..7
    uint4 c1 = c4[1];
    uint4 d0 = c4[2];   // cell k0+5, f0..7
    uint4 d1 = c4[3];

    float m[16];
#pragma unroll
    for (int f = 0; f < 16; ++f) m[f] = 0.f;

    fma_bf2(a0.x, t00, m[0], m[1]);  fma_bf2(a0.y, t00, m[2], m[3]);
    fma_bf2(a0.z, t00, m[4], m[5]);  fma_bf2(a0.w, t00, m[6], m[7]);
    fma_bf2(a1.x, t00, m[8], m[9]);  fma_bf2(a1.y, t00, m[10], m[11]);
    fma_bf2(a1.z, t00, m[12], m[13]);fma_bf2(a1.w, t00, m[14], m[15]);

    fma_bf2(b0.x, t01, m[0], m[1]);  fma_bf2(b0.y, t01, m[2], m[3]);
    fma_bf2(b0.z, t01, m[4], m[5]);  fma_bf2(b0.w, t01, m[6], m[7]);
    fma_bf2(b1.x, t01, m[8], m[9]);  fma_bf2(b1.y, t01, m[10], m[11]);
    fma_bf2(b1.z, t01, m[12], m[13]);fma_bf2(b1.w, t01, m[14], m[15]);

    fma_bf2(c0.x, t10, m[0], m[1]);  fma_bf2(c0.y, t10, m[2], m[3]);
    fma_bf2(c0.z, t10, m[4], m[5]);  fma_bf2(c0.w, t10, m[6], m[7]);
    fma_bf2(c1.x, t10, m[8], m[9]);  fma_bf2(c1.y, t10, m[10], m[11]);
    fma_bf2(c1.z, t10, m[12], m[13]);fma_bf2(c1.w, t10, m[14], m[15]);

    fma_bf2(d0.x, t11, m[0], m[1]);  fma_bf2(d0.y, t11, m[2], m[3]);
    fma_bf2(d0.z, t11, m[4], m[5]);  fma_bf2(d0.w, t11, m[6], m[7]);
    fma_bf2(d1.x, t11, m[8], m[9]);  fma_bf2(d1.y, t11, m[10], m[11]);
    fma_bf2(d1.z, t11, m[12], m[13]);fma_bf2(d1.w, t11, m[14], m[15]);

    float* op = out + (size_t)row * 16;
#pragma unroll
    for (int f = 0; f < 16; ++f) unsafeAtomicAdd(op + f, m[f]);
}

// ---------------- Fallback (R2 kernel) if ws_size < Y_BYTES ----------------
#define FSLAB 260
__global__ __launch_bounds__(256) void basis_conv_edges(
    const float* __restrict__ x, const int* __restrict__ edge_index,
    const float* __restrict__ edge_attr, const float* __restrict__ weight,
    float* __restrict__ out)
{
    __shared__ float wl[16 * FSLAB];
    for (int idx = threadIdx.x; idx < 4096; idx += 256) {
        const int f = idx & 15, i = (idx >> 4) & 15, k = idx >> 8;
        wl[f * FSLAB + k * 16 + i] = weight[idx];
    }
    __syncthreads();
    const int f = threadIdx.x & 15, s = threadIdx.x >> 4;
    const int ebase = blockIdx.x * 256;
#pragma unroll 1
    for (int it = 0; it < 16; ++it) {
        const int e = ebase + it * 16 + s;
        const int row = edge_index[e];
        const int col = edge_index[N_EDGES + e];
        const float2 attr = ((const float2*)edge_attr)[e];
        float fu = (attr.x + 1.0f) * 1.5f;
        int iu = (int)fu; iu = iu < 0 ? 0 : (iu > 2 ? 2 : iu);
        const float wu1 = fu - (float)iu, wu0 = 1.0f - wu1;
        float fv = (attr.y + 1.0f) * 1.5f;
        int iv = (int)fv; iv = iv < 0 ? 0 : (iv > 2 ? 2 : iv);
        const float wv1 = fv - (float)iv, wv0 = 1.0f - wv1;
        const int k0 = iu * 4 + iv;
        int kb[4] = {k0, k0 + 1, k0 + 4, k0 + 5};
        float tw[4] = {wu0 * wv0, wu0 * wv1, wu1 * wv0, wu1 * wv1};
        const float4* xv = (const float4*)(x + (size_t)col * 16);
        float xs[16];
#pragma unroll
        for (int q = 0; q < 4; ++q) {
            float4 t4 = xv[q];
            xs[4*q+0]=t4.x; xs[4*q+1]=t4.y; xs[4*q+2]=t4.z; xs[4*q+3]=t4.w;
        }
        float msg = 0.0f;
#pragma unroll
        for (int p = 0; p < 4; ++p) {
            const float t = tw[p];
            const float4* wp = (const float4*)&wl[f * FSLAB + kb[p] * 16];
#pragma unroll
            for (int i4 = 0; i4 < 4; ++i4) {
                const float4 w = wp[i4];
                msg += t * (xs[4*i4+0]*w.x + xs[4*i4+1]*w.y + xs[4*i4+2]*w.z + xs[4*i4+3]*w.w);
            }
        }
        unsafeAtomicAdd(out + (size_t)row * 16 + f, msg);
    }
}

extern "C" void kernel_launch(void* const* d_in, const int* in_sizes, int n_in,
                              void* d_out, int out_size, void* d_ws, size_t ws_size,
                              hipStream_t stream) {
    const float* x  = (const float*)d_in[0];
    const int*   ei = (const int*)d_in[1];
    const float* ea = (const float*)d_in[2];
    const float* w  = (const float*)d_in[3];
    float* out = (float*)d_out;

    const int n4 = out_size / 4;
    zero_out_kernel<<<(n4 + 255) / 256, 256, 0, stream>>>((float4*)out, n4);

    if (ws_size >= Y_BYTES) {
        unsigned short* Y = (unsigned short*)d_ws;
        stage1_xw<<<1024, 256, 0, stream>>>(x, w, Y);
        stage2_edges<<<N_EDGES / 256, 256, 0, stream>>>(ei, ea, Y, out);
    } else {
        basis_conv_edges<<<N_EDGES / 256, 256, 0, stream>>>(x, ei, ea, w, out);
    }
}

// Round 4
// 194.089 us; speedup vs baseline: 7.3788x; 7.3788x over previous
//
#include <hip/hip_runtime.h>
#include <hip/hip_bf16.h>

#define N_NODES 100000
#define N_EDGES 1600000
#define Y_ELEMS (16 * N_NODES * 16)            // Y[n][k][f]
#define Y_BYTES ((size_t)Y_ELEMS * 2)          // 51.2 MB bf16

__global__ __launch_bounds__(256) void zero_out_kernel(float4* __restrict__ out, int n4) {
    int i = blockIdx.x * 256 + threadIdx.x;
    if (i < n4) out[i] = make_float4(0.f, 0.f, 0.f, 0.f);
}

__device__ __forceinline__ unsigned short f2bf(float f) {
    __hip_bfloat16 h = __float2bfloat16(f);
    return *(unsigned short*)&h;
}
__device__ __forceinline__ float bf2f(unsigned short u) {
    return __uint_as_float(((unsigned int)u) << 16);
}

// Stage 1: Y[n][k][f] (bf16) = sum_i x[n][i] * W[k][i][f]
// wave-per-node: 64 lanes = 16 k-cells x 4 f-quads; W held in registers,
// amortized over ~25 nodes per wave.
__global__ __launch_bounds__(256) void stage1_xw(
    const float* __restrict__ x,       // [N_NODES,16]
    const float* __restrict__ w,       // [16][16][16] = [k][i][f]
    unsigned short* __restrict__ Y)    // [N_NODES][16][16] bf16
{
    const int lane = threadIdx.x & 63;
    const int k  = lane >> 2;          // 0..15
    const int fq = lane & 3;           // 0..3
    const int gwave  = blockIdx.x * 4 + (threadIdx.x >> 6);
    const int nwaves = gridDim.x * 4;

    float4 wr[16];
#pragma unroll
    for (int i = 0; i < 16; ++i)
        wr[i] = *(const float4*)(w + k * 256 + i * 16 + fq * 4);

    for (int n = gwave; n < N_NODES; n += nwaves) {
        const float4* xr = (const float4*)(x + (size_t)n * 16);
        float xs[16];
#pragma unroll
        for (int q = 0; q < 4; ++q) {
            float4 t4 = xr[q];
            xs[4*q+0] = t4.x; xs[4*q+1] = t4.y; xs[4*q+2] = t4.z; xs[4*q+3] = t4.w;
        }
        float4 acc = make_float4(0.f, 0.f, 0.f, 0.f);
#pragma unroll
        for (int i = 0; i < 16; ++i) {
            acc.x += xs[i] * wr[i].x; acc.y += xs[i] * wr[i].y;
            acc.z += xs[i] * wr[i].z; acc.w += xs[i] * wr[i].w;
        }
        ushort4 o;
        o.x = f2bf(acc.x); o.y = f2bf(acc.y); o.z = f2bf(acc.z); o.w = f2bf(acc.w);
        *(ushort4*)(Y + (size_t)n * 256 + k * 16 + fq * 4) = o;
    }
}

// Stage 2: 16 lanes per edge, lane = output feature f.
// Gather: 4 bf16 scalars Y[col][kb][f]; 16 lanes/edge -> one 32B sector/cell.
// Scatter: 1 atomic/lane, 16 contiguous floats per edge -> fully-dirty lines
// (R2's pattern: WRITE_SIZE = 4B/atomic, not 32B).
__global__ __launch_bounds__(256) void stage2_fanout(
    const int*   __restrict__ edge_index,  // [2, N_EDGES]
    const float* __restrict__ edge_attr,   // [N_EDGES, 2]
    const unsigned short* __restrict__ Y,  // [N_NODES][16][16] bf16
    float*       __restrict__ out)         // [N_NODES,16], pre-zeroed
{
    const int g = blockIdx.x * 256 + threadIdx.x;
    const int e = g >> 4;            // edge index (grid sized exactly)
    const int f = g & 15;            // output feature

    const int row = edge_index[e];
    const int col = edge_index[N_EDGES + e];
    const float2 attr = ((const float2*)edge_attr)[e];

    float fu = (attr.x + 1.0f) * 1.5f;
    int iu = (int)fu; iu = iu < 0 ? 0 : (iu > 2 ? 2 : iu);
    const float wu1 = fu - (float)iu;
    const float wu0 = 1.0f - wu1;

    float fv = (attr.y + 1.0f) * 1.5f;
    int iv = (int)fv; iv = iv < 0 ? 0 : (iv > 2 ? 2 : iv);
    const float wv1 = fv - (float)iv;
    const float wv0 = 1.0f - wv1;

    const int k0 = iu * 4 + iv;
    const unsigned short* yb = Y + (size_t)col * 256 + f;

    const float y00 = bf2f(yb[(k0)     * 16]);
    const float y01 = bf2f(yb[(k0 + 1) * 16]);
    const float y10 = bf2f(yb[(k0 + 4) * 16]);
    const float y11 = bf2f(yb[(k0 + 5) * 16]);

    const float msg = (wu0 * wv0) * y00 + (wu0 * wv1) * y01 +
                      (wu1 * wv0) * y10 + (wu1 * wv1) * y11;

    unsafeAtomicAdd(out + (size_t)row * 16 + f, msg);
}

// ---------------- Fallback (R2 kernel) if ws_size < Y_BYTES ----------------
#define FSLAB 260
__global__ __launch_bounds__(256) void basis_conv_edges(
    const float* __restrict__ x, const int* __restrict__ edge_index,
    const float* __restrict__ edge_attr, const float* __restrict__ weight,
    float* __restrict__ out)
{
    __shared__ float wl[16 * FSLAB];
    for (int idx = threadIdx.x; idx < 4096; idx += 256) {
        const int f = idx & 15, i = (idx >> 4) & 15, k = idx >> 8;
        wl[f * FSLAB + k * 16 + i] = weight[idx];
    }
    __syncthreads();
    const int f = threadIdx.x & 15, s = threadIdx.x >> 4;
    const int ebase = blockIdx.x * 256;
#pragma unroll 1
    for (int it = 0; it < 16; ++it) {
        const int e = ebase + it * 16 + s;
        const int row = edge_index[e];
        const int col = edge_index[N_EDGES + e];
        const float2 attr = ((const float2*)edge_attr)[e];
        float fu = (attr.x + 1.0f) * 1.5f;
        int iu = (int)fu; iu = iu < 0 ? 0 : (iu > 2 ? 2 : iu);
        const float wu1 = fu - (float)iu, wu0 = 1.0f - wu1;
        float fv = (attr.y + 1.0f) * 1.5f;
        int iv = (int)fv; iv = iv < 0 ? 0 : (iv > 2 ? 2 : iv);
        const float wv1 = fv - (float)iv, wv0 = 1.0f - wv1;
        const int k0 = iu * 4 + iv;
        int kb[4] = {k0, k0 + 1, k0 + 4, k0 + 5};
        float tw[4] = {wu0 * wv0, wu0 * wv1, wu1 * wv0, wu1 * wv1};
        const float4* xv = (const float4*)(x + (size_t)col * 16);
        float xs[16];
#pragma unroll
        for (int q = 0; q < 4; ++q) {
            float4 t4 = xv[q];
            xs[4*q+0]=t4.x; xs[4*q+1]=t4.y; xs[4*q+2]=t4.z; xs[4*q+3]=t4.w;
        }
        float msg = 0.0f;
#pragma unroll
        for (int p = 0; p < 4; ++p) {
            const float t = tw[p];
            const float4* wp = (const float4*)&wl[f * FSLAB + kb[p] * 16];
#pragma unroll
            for (int i4 = 0; i4 < 4; ++i4) {
                const float4 w = wp[i4];
                msg += t * (xs[4*i4+0]*w.x + xs[4*i4+1]*w.y + xs[4*i4+2]*w.z + xs[4*i4+3]*w.w);
            }
        }
        unsafeAtomicAdd(out + (size_t)row * 16 + f, msg);
    }
}

extern "C" void kernel_launch(void* const* d_in, const int* in_sizes, int n_in,
                              void* d_out, int out_size, void* d_ws, size_t ws_size,
                              hipStream_t stream) {
    const float* x  = (const float*)d_in[0];
    const int*   ei = (const int*)d_in[1];
    const float* ea = (const float*)d_in[2];
    const float* w  = (const float*)d_in[3];
    float* out = (float*)d_out;

    const int n4 = out_size / 4;
    zero_out_kernel<<<(n4 + 255) / 256, 256, 0, stream>>>((float4*)out, n4);

    if (ws_size >= Y_BYTES) {
        unsigned short* Y = (unsigned short*)d_ws;
        stage1_xw<<<1024, 256, 0, stream>>>(x, w, Y);
        // 16 threads per edge: grid = N_EDGES*16/256 = 100000 blocks
        stage2_fanout<<<(N_EDGES * 16) / 256, 256, 0, stream>>>(ei, ea, Y, out);
    } else {
        basis_conv_edges<<<N_EDGES / 256, 256, 0, stream>>>(x, ei, ea, w, out);
    }
}